// Round 8
// baseline (35168.161 us; speedup 1.0000x reference)
//
#include <hip/hip_runtime.h>
#include <hip/hip_bf16.h>
#include <cstdint>

// Problem dims
#define TE    512
#define SD    128
#define NB    512   // persistent grid (2 blocks/CU x 256 CUs)

typedef unsigned short u16;
typedef u16 u16x4 __attribute__((ext_vector_type(4)));
typedef u16 u16x8 __attribute__((ext_vector_type(8)));

// State region offsets (floats), st = d_ws + 67,108,864 B (ws >= 68.1 MB proven r5-r7)
#define QO    0          // [32][1024]
#define SCO   32768      // [32][512]
#define BARO  49152      // barrier counter (int), own region
#define CTXO  81920      // [32][1024]
#define YO    114688     // [32][128]
#define H0O   118784     // [2][32][512]
#define C0O   151552
#define H1O   184320
#define C1O   217088
#define ST_N  249856

__device__ __forceinline__ float b2f(u16 v) { return __uint_as_float(((unsigned)v) << 16); }
__device__ __forceinline__ u16 f2b(float f) {
  unsigned u = __float_as_uint(f);
  return (u16)((u + 0x7FFFu + ((u >> 16) & 1u)) >> 16);
}
__device__ __forceinline__ float tanh_f(float x) {
  float xc = fminf(12.f, fmaxf(-12.f, x));
  float e  = __expf(2.f * xc);
  return __fdividef(e - 1.f, e + 1.f);
}
__device__ __forceinline__ float sigm(float x) {
  float xc = fminf(30.f, fmaxf(-30.f, x));
  return __fdividef(1.f, 1.f + __expf(-xc));
}

// ---------------- NT GEMM: key=E@Wk^T, value=E@Wv^T (fp32 in, bf16 out) ----------------
__global__ __launch_bounds__(256)
void gemm_kv(const float* __restrict__ E, const float* __restrict__ Wk,
             const float* __restrict__ Wv, u16* __restrict__ key, u16* __restrict__ value) {
  const float* B = blockIdx.z ? Wv : Wk;
  u16* outp = blockIdx.z ? value : key;
  __shared__ float Asm[16][68], Bsm[16][68];
  const int tid = threadIdx.x;
  const int tm = blockIdx.x * 64, tn = blockIdx.y * 64;
  const int lr = tid >> 2, lc = (tid & 3) * 4;
  const int tx = tid & 15, ty = tid >> 4;
  float acc[4][4] = {};
  for (int k0 = 0; k0 < 1024; k0 += 16) {
    float4 av = *(const float4*)(&E[(long)(tm + lr) * 1024 + k0 + lc]);
    float4 bv = *(const float4*)(&B[(long)(tn + lr) * 1024 + k0 + lc]);
    Asm[lc][lr] = av.x; Asm[lc + 1][lr] = av.y; Asm[lc + 2][lr] = av.z; Asm[lc + 3][lr] = av.w;
    Bsm[lc][lr] = bv.x; Bsm[lc + 1][lr] = bv.y; Bsm[lc + 2][lr] = bv.z; Bsm[lc + 3][lr] = bv.w;
    __syncthreads();
#pragma unroll
    for (int kk = 0; kk < 16; ++kk) {
      float4 a4 = *(const float4*)(&Asm[kk][ty * 4]);
      float4 b4 = *(const float4*)(&Bsm[kk][tx * 4]);
      acc[0][0] += a4.x * b4.x; acc[0][1] += a4.x * b4.y; acc[0][2] += a4.x * b4.z; acc[0][3] += a4.x * b4.w;
      acc[1][0] += a4.y * b4.x; acc[1][1] += a4.y * b4.y; acc[1][2] += a4.y * b4.z; acc[1][3] += a4.y * b4.w;
      acc[2][0] += a4.z * b4.x; acc[2][1] += a4.z * b4.y; acc[2][2] += a4.z * b4.z; acc[2][3] += a4.z * b4.w;
      acc[3][0] += a4.w * b4.x; acc[3][1] += a4.w * b4.y; acc[3][2] += a4.w * b4.z; acc[3][3] += a4.w * b4.w;
    }
    __syncthreads();
  }
#pragma unroll
  for (int i = 0; i < 4; ++i)
#pragma unroll
    for (int j = 0; j < 4; ++j)
      outp[(long)(tm + ty * 4 + i) * 1024 + tn + tx * 4 + j] = f2b(acc[i][j]);
}

// ---------------- init: h/c -> parity-0 state, zero y + barrier ----------------
__global__ __launch_bounds__(256)
void init_state(const float* __restrict__ h0, const float* __restrict__ c0, float* __restrict__ st) {
  int i = blockIdx.x * 256 + threadIdx.x;   // 16384 threads
  st[H0O + i] = h0[i];
  st[H1O + i] = h0[16384 + i];
  st[C0O + i] = c0[i];
  st[C1O + i] = c0[16384 + i];
  if (i < 4096) st[YO + i] = 0.f;
  if (i < 256) ((int*)(st + BARO))[i] = 0;
}

// ---------------- q0 = h0_layer0 @ Wq^T ----------------
__global__ __launch_bounds__(256)
void qproj(const float* __restrict__ h0, const float* __restrict__ Wq, float* __restrict__ st) {
  __shared__ float hr[512];
  const int b = blockIdx.x >> 2, o = (blockIdx.x & 3) * 256 + threadIdx.x;
  for (int i = threadIdx.x; i < 512; i += 256) hr[i] = h0[b * 512 + i];
  __syncthreads();
  float acc = 0.f;
  for (int k = 0; k < 512; k += 4) {
    float4 wv = *(const float4*)(&Wq[(long)o * 512 + k]);
    acc += hr[k] * wv.x + hr[k + 1] * wv.y + hr[k + 2] * wv.z + hr[k + 3] * wv.w;
  }
  st[QO + b * 1024 + o] = acc;
}

// ---------------- grid barrier: monotone counter, relaxed polls, single fences ----------------
// rounds 5/6 post-mortem: ACQUIRE-ordered poll loads emit a per-XCD L2 invalidate
// EVERY iteration (100-300us/barrier). Here: exactly one release fence (wbl2) before
// arrival + one acquire fence (inv) after wait; polls are RELAXED fabric reads.
__device__ __forceinline__ void gbar(int* bar, int target) {
  __syncthreads();   // drains each wave's vmcnt -> block's stores are in L2
  if (threadIdx.x == 0) {
    __builtin_amdgcn_fence(__ATOMIC_RELEASE, "agent");   // one L2 writeback
    __hip_atomic_fetch_add(bar, 1, __ATOMIC_RELAXED, __HIP_MEMORY_SCOPE_AGENT);
    while (__hip_atomic_load(bar, __ATOMIC_RELAXED, __HIP_MEMORY_SCOPE_AGENT) < target)
      __builtin_amdgcn_s_sleep(8);
    __builtin_amdgcn_fence(__ATOMIC_ACQUIRE, "agent");   // one L1/L2 invalidate
  }
  __syncthreads();
}

// ---------------- fc: y_hat = relu(h1 @ fc_w^T + b); out + y update ----------------
__device__ void fc_do(const float* __restrict__ fcw, const float* __restrict__ fcb,
                      float* __restrict__ st, float* __restrict__ out,
                      int b, int srow, int hp, int tid, int wv, int ln, float* sm) {
  float* h1s = sm;
  for (int i = tid; i < 512; i += 256) h1s[i] = st[H1O + hp * 16384 + b * 512 + i];
  __syncthreads();
  for (int oi = 0; oi < 32; ++oi) {
    const int o = wv * 32 + oi;
    float part = 0.f;
#pragma unroll
    for (int kk = 0; kk < 8; ++kk) {
      int k = kk * 64 + ln;
      part += h1s[k] * fcw[(long)o * 512 + k];
    }
    for (int off = 32; off; off >>= 1) part += __shfl_down(part, off);
    if (ln == 0) {
      float yh = fmaxf(part + fcb[o], 0.f);
      out[((long)b * SD + srow) * 128 + o] = yh;
      st[YO + b * 128 + o] = 1.f + yh;
    }
  }
  __syncthreads();
}

// ---------------- persistent decode: all 128 steps, 4 grid barriers each ----------------
__global__ __launch_bounds__(256, 2)
void decode_all(const u16* __restrict__ key, const u16* __restrict__ value,
                const float* __restrict__ We, const float* __restrict__ Wq,
                const float* __restrict__ wih0, const float* __restrict__ whh0,
                const float* __restrict__ bih0, const float* __restrict__ bhh0,
                const float* __restrict__ wih1, const float* __restrict__ whh1,
                const float* __restrict__ bih1, const float* __restrict__ bhh1,
                const float* __restrict__ fcw, const float* __restrict__ fcb,
                float* __restrict__ st, float* __restrict__ out) {
  __shared__ float sm[5792];
  int* bar = (int*)(st + BARO);
  const int bid = blockIdx.x, tid = threadIdx.x;
  const int wv = tid >> 6, ln = tid & 63;
  int bnum = 0;

  for (int s = 0; s < SD; ++s) {
    const int p = s & 1;

    // ---- A: scores (512 blocks = 32 b x 16 t-chunks), pairwise-unrolled ----
    {
      const int b = bid >> 4, tc = bid & 15, t0 = tc * 32;
      float qr[16], wer[16];
      const float* qp = st + QO + b * 1024 + ln * 16;
#pragma unroll
      for (int j = 0; j < 16; ++j) qr[j] = qp[j];
#pragma unroll
      for (int j = 0; j < 16; j += 4) {
        float4 w4 = *(const float4*)(&We[ln * 16 + j]);
        wer[j] = w4.x; wer[j + 1] = w4.y; wer[j + 2] = w4.z; wer[j + 3] = w4.w;
      }
      const u16* kbase = key + ((long)(b * TE + t0) << 10) + ln * 16;
#pragma unroll
      for (int u = 0; u < 4; ++u) {
        const int tt0 = wv + u * 8, tt1 = wv + u * 8 + 4;
        const u16* kr0 = kbase + ((long)tt0 << 10);
        const u16* kr1 = kbase + ((long)tt1 << 10);
        u16x8 a0 = *(const u16x8*)kr0, a1 = *(const u16x8*)(kr0 + 8);
        u16x8 b0 = *(const u16x8*)kr1, b1 = *(const u16x8*)(kr1 + 8);
        float p0 = 0.f, p1 = 0.f;
#pragma unroll
        for (int j = 0; j < 8; ++j) {
          p0 += tanh_f(qr[j] + b2f(a0[j])) * wer[j];
          p1 += tanh_f(qr[j] + b2f(b0[j])) * wer[j];
        }
#pragma unroll
        for (int j = 0; j < 8; ++j) {
          p0 += tanh_f(qr[8 + j] + b2f(a1[j])) * wer[8 + j];
          p1 += tanh_f(qr[8 + j] + b2f(b1[j])) * wer[8 + j];
        }
        for (int off = 32; off; off >>= 1) {
          p0 += __shfl_down(p0, off);
          p1 += __shfl_down(p1, off);
        }
        if (ln == 0) {
          st[SCO + b * 512 + t0 + tt0] = p0;
          st[SCO + b * 512 + t0 + tt1] = p1;
        }
      }
    }
    gbar(bar, (++bnum) * NB);

    // ---- B: softmax + ctx = alpha @ value (blocks 0-255) ; fc(s-1) (blocks 256-287) ----
    if (bid < 256) {
      const int b = bid >> 3, dc = bid & 7;
      float* al = sm; float* rr = sm + 512; float* gp = sm + 520;
      al[tid]       = st[SCO + b * 512 + tid];
      al[tid + 256] = st[SCO + b * 512 + tid + 256];
      __syncthreads();
      float m = fmaxf(al[tid], al[tid + 256]);
      for (int off = 32; off; off >>= 1) m = fmaxf(m, __shfl_xor(m, off));
      if (ln == 0) rr[wv] = m;
      __syncthreads();
      const float M = fmaxf(fmaxf(rr[0], rr[1]), fmaxf(rr[2], rr[3]));
      float e0 = __expf(al[tid] - M), e1 = __expf(al[tid + 256] - M);
      float l = e0 + e1;
      for (int off = 32; off; off >>= 1) l += __shfl_xor(l, off);
      if (ln == 0) rr[4 + wv] = l;
      __syncthreads();
      const float inv = __fdividef(1.f, rr[4] + rr[5] + rr[6] + rr[7]);
      al[tid] = e0; al[tid + 256] = e1;
      __syncthreads();
      const int dl = (tid & 31) * 4, tg = tid >> 5;
      float a0 = 0.f, a1 = 0.f, a2 = 0.f, a3 = 0.f;
      const u16* vb = value + ((long)(b * TE) << 10) + dc * 128 + dl;
#pragma unroll 4
      for (int t = tg; t < 512; t += 8) {
        u16x4 vvv = *(const u16x4*)(vb + ((long)t << 10));
        float av = al[t];
        a0 += av * b2f(vvv[0]); a1 += av * b2f(vvv[1]);
        a2 += av * b2f(vvv[2]); a3 += av * b2f(vvv[3]);
      }
      float4 a4 = {a0, a1, a2, a3};
      *(float4*)(&gp[tg * 132 + dl]) = a4;
      __syncthreads();
      if (tid < 128) {
        float ssum = 0.f;
#pragma unroll
        for (int g = 0; g < 8; ++g) ssum += gp[g * 132 + tid];
        st[CTXO + b * 1024 + dc * 128 + tid] = ssum * inv;
      }
    } else if (bid < 288) {
      if (s > 0) fc_do(fcw, fcb, st, out, bid - 256, s - 1, p, tid, wv, ln, sm);
    }
    gbar(bar, (++bnum) * NB);

    // ---- C: LSTM0 (512 blocks, block = h-dim) ----
    {
      const int h = bid;
      float* xs = sm; float* wr = sm + 4224; float* gp = sm + 4752;
      float acc[4] = {0.f, 0.f, 0.f, 0.f};
      for (int ch = 0; ch < 13; ++ch) {
        const float* src; int stride, col0;
        if (ch == 0)      { src = st + YO;               stride = 128;  col0 = 0; }
        else if (ch <= 8) { src = st + CTXO;             stride = 1024; col0 = (ch - 1) * 128; }
        else              { src = st + H0O + p * 16384;  stride = 512;  col0 = (ch - 9) * 128; }
#pragma unroll
        for (int i = 0; i < 4; ++i) {
          int e4 = tid * 4 + i * 1024;
          int bs = e4 >> 7, j = e4 & 127;
          *(float4*)(&xs[bs * 132 + j]) = *(const float4*)(src + bs * stride + col0 + j);
        }
        {
          int e = tid * 2, r = e >> 7, j = e & 127;  // 4 rows x 128
          const float* wsrc; long rb;
          if (ch <= 8) { wsrc = wih0; rb = (long)(r * 512 + h) * 1152 + ch * 128; }
          else         { wsrc = whh0; rb = (long)(r * 512 + h) * 512 + (ch - 9) * 128; }
          *(float2*)(&wr[r * 132 + j]) = *(const float2*)(&wsrc[rb + j]);
        }
        __syncthreads();
        const int b = tid & 31, j0 = (tid >> 5) * 16;
#pragma unroll
        for (int jj = 0; jj < 16; jj += 4) {
          const float4 xv = *(const float4*)(&xs[b * 132 + j0 + jj]);
#pragma unroll
          for (int r = 0; r < 4; ++r) {
            const float4 w4 = *(const float4*)(&wr[r * 132 + j0 + jj]);
            acc[r] += xv.x * w4.x + xv.y * w4.y + xv.z * w4.z + xv.w * w4.w;
          }
        }
        __syncthreads();
      }
#pragma unroll
      for (int r = 0; r < 4; ++r) acc[r] += __shfl_down(acc[r], 32);
      if (ln < 32) {
#pragma unroll
        for (int r = 0; r < 4; ++r) gp[(wv * 32 + ln) * 4 + r] = acc[r];
      }
      __syncthreads();
      if (tid < 32) {
        const int b = tid;
        float gg[4];
#pragma unroll
        for (int g = 0; g < 4; ++g)
          gg[g] = gp[(0 * 32 + b) * 4 + g] + gp[(1 * 32 + b) * 4 + g] +
                  gp[(2 * 32 + b) * 4 + g] + gp[(3 * 32 + b) * 4 + g] +
                  bih0[g * 512 + h] + bhh0[g * 512 + h];
        float ig = sigm(gg[0]), fg = sigm(gg[1]), gt = tanh_f(gg[2]), og = sigm(gg[3]);
        int si = b * 512 + h;
        float c  = st[C0O + p * 16384 + si];
        float cn = fg * c + ig * gt;
        float hn = og * tanh_f(cn);
        st[H0O + (p ^ 1) * 16384 + si] = hn;
        st[C0O + (p ^ 1) * 16384 + si] = cn;
      }
      __syncthreads();
    }
    gbar(bar, (++bnum) * NB);

    // ---- D: LSTM1 + q_next (512 blocks, block = h-dim, 2 q-rows) ----
    {
      const int h = bid;
      float* xs = sm; float* wr = sm + 4224; float* gp = sm + 5016;
      float acc[6] = {0.f, 0.f, 0.f, 0.f, 0.f, 0.f};
      for (int ch = 0; ch < 8; ++ch) {
        const float* src = (ch < 4) ? (st + H0O + (p ^ 1) * 16384) : (st + H1O + p * 16384);
        const int col0 = (ch & 3) * 128;
#pragma unroll
        for (int i = 0; i < 4; ++i) {
          int e4 = tid * 4 + i * 1024;
          int bs = e4 >> 7, j = e4 & 127;
          *(float4*)(&xs[bs * 132 + j]) = *(const float4*)(src + bs * 512 + col0 + j);
        }
        {
          int e = tid * 2, r = e >> 7, j = e & 127;
          const float* wsrc = (ch < 4) ? wih1 : whh1;
          long rb = (long)(r * 512 + h) * 512 + col0;
          *(float2*)(&wr[r * 132 + j]) = *(const float2*)(&wsrc[rb + j]);
          if (ch < 4) {
            int rq = tid >> 7, j2 = tid & 127;  // 2 rows x 128
            wr[(4 + rq) * 132 + j2] = Wq[(long)(2 * h + rq) * 512 + col0 + j2];
          }
        }
        __syncthreads();
        const int b = tid & 31, j0 = (tid >> 5) * 16;
#pragma unroll
        for (int jj = 0; jj < 16; jj += 4) {
          const float4 xv = *(const float4*)(&xs[b * 132 + j0 + jj]);
#pragma unroll
          for (int r = 0; r < 4; ++r) {
            const float4 w4 = *(const float4*)(&wr[r * 132 + j0 + jj]);
            acc[r] += xv.x * w4.x + xv.y * w4.y + xv.z * w4.z + xv.w * w4.w;
          }
          if (ch < 4) {
#pragma unroll
            for (int r = 4; r < 6; ++r) {
              const float4 w4 = *(const float4*)(&wr[r * 132 + j0 + jj]);
              acc[r] += xv.x * w4.x + xv.y * w4.y + xv.z * w4.z + xv.w * w4.w;
            }
          }
        }
        __syncthreads();
      }
#pragma unroll
      for (int r = 0; r < 6; ++r) acc[r] += __shfl_down(acc[r], 32);
      if (ln < 32) {
#pragma unroll
        for (int r = 0; r < 6; ++r) gp[(wv * 32 + ln) * 6 + r] = acc[r];
      }
      __syncthreads();
      if (tid < 32) {
        const int b = tid;
        float gg[4];
#pragma unroll
        for (int g = 0; g < 4; ++g)
          gg[g] = gp[(0 * 32 + b) * 6 + g] + gp[(1 * 32 + b) * 6 + g] +
                  gp[(2 * 32 + b) * 6 + g] + gp[(3 * 32 + b) * 6 + g] +
                  bih1[g * 512 + h] + bhh1[g * 512 + h];
        float ig = sigm(gg[0]), fg = sigm(gg[1]), gt = tanh_f(gg[2]), og = sigm(gg[3]);
        int si = b * 512 + h;
        float c  = st[C1O + p * 16384 + si];
        float cn = fg * c + ig * gt;
        float hn = og * tanh_f(cn);
        st[H1O + (p ^ 1) * 16384 + si] = hn;
        st[C1O + (p ^ 1) * 16384 + si] = cn;
        float q0 = gp[(0 * 32 + b) * 6 + 4] + gp[(1 * 32 + b) * 6 + 4] +
                   gp[(2 * 32 + b) * 6 + 4] + gp[(3 * 32 + b) * 6 + 4];
        float q1 = gp[(0 * 32 + b) * 6 + 5] + gp[(1 * 32 + b) * 6 + 5] +
                   gp[(2 * 32 + b) * 6 + 5] + gp[(3 * 32 + b) * 6 + 5];
        st[QO + b * 1024 + 2 * h]     = q0;
        st[QO + b * 1024 + 2 * h + 1] = q1;
      }
      __syncthreads();
    }
    gbar(bar, (++bnum) * NB);
  }

  // final fc for step SD-1 (h1[127] at parity 0)
  if (bid >= 256 && bid < 288)
    fc_do(fcw, fcb, st, out, bid - 256, SD - 1, 0, tid, wv, ln, sm);
}

extern "C" void kernel_launch(void* const* d_in, const int* in_sizes, int n_in,
                              void* d_out, int out_size, void* d_ws, size_t ws_size,
                              hipStream_t stream) {
  (void)in_sizes; (void)n_in; (void)out_size; (void)ws_size;
  float* out = (float*)d_out;

  const float* E    = (const float*)d_in[0];
  const float* h0   = (const float*)d_in[1];
  const float* c0   = (const float*)d_in[2];
  const float* Wk   = (const float*)d_in[3];
  const float* Wq   = (const float*)d_in[4];
  const float* Wv   = (const float*)d_in[5];
  const float* We   = (const float*)d_in[6];
  const float* wih0 = (const float*)d_in[7];
  const float* whh0 = (const float*)d_in[8];
  const float* bih0 = (const float*)d_in[9];
  const float* bhh0 = (const float*)d_in[10];
  const float* wih1 = (const float*)d_in[11];
  const float* whh1 = (const float*)d_in[12];
  const float* bih1 = (const float*)d_in[13];
  const float* bhh1 = (const float*)d_in[14];
  const float* fcw  = (const float*)d_in[15];
  const float* fcb  = (const float*)d_in[16];

  // ws layout (>= 68.1 MB proven): key bf16 33.5MB | value bf16 33.5MB | st ~1MB
  u16* key   = (u16*)d_ws;
  u16* value = key + 16777216;
  float* st  = (float*)d_ws + 16777216;   // byte 67,108,864

  gemm_kv<<<dim3(256, 16, 2), 256, 0, stream>>>(E, Wk, Wv, key, value);
  init_state<<<64, 256, 0, stream>>>(h0, c0, st);
  qproj<<<128, 256, 0, stream>>>(h0, Wq, st);
  decode_all<<<NB, 256, 0, stream>>>(key, value, We, Wq, wih0, whh0, bih0, bhh0,
                                     wih1, whh1, bih1, bhh1, fcw, fcb, st, out);
}